// Round 11
// baseline (68.806 us; speedup 1.0000x reference)
//
#include <hip/hip_runtime.h>
#include <math.h>

#define T     600
#define C     14
#define NOUT  500
#define W     128
#define DSTR  132        // D row stride (floats): bank spread, 528B = 16B-aligned rows
#define CAP   64

typedef float f32x2 __attribute__((ext_vector_type(2)));

__device__ __forceinline__ f32x2 fma2(f32x2 a, f32x2 b, f32x2 c) {
#if __has_builtin(__builtin_elementwise_fma)
    return __builtin_elementwise_fma(a, b, c);
#else
    f32x2 r; r.x = fmaf(a.x, b.x, c.x); r.y = fmaf(a.y, b.y, c.y); return r;
#endif
}
__device__ __forceinline__ f32x2 wp(float w) { f32x2 r; r.x = w; r.y = w; return r; }

struct SR { float u; int e; };

// cold exact replay of one 16-step batch (wave-uniform rare call)
__device__ __noinline__ SR slow_replay(float u, float4 h0, float4 h1, float4 h2,
                                       float4 h3, int tb, int lane, int ecnt,
                                       unsigned* evp) {
    float h[16] = {h0.x,h0.y,h0.z,h0.w, h1.x,h1.y,h1.z,h1.w,
                   h2.x,h2.y,h2.z,h2.w, h3.x,h3.y,h3.z,h3.w};
    #pragma unroll
    for (int i = 0; i < 16; ++i) {
        u = fmaf(u, 0.5f, h[i]);
        const unsigned long long bal = __ballot(u >= 14.0f);
        if (bal) {
            if (u >= 14.0f) u = 1.0f;        // reset (u=2v) + exact feedback fold
            if (lane == 0 && ecnt < CAP)
                evp[ecnt] = ((unsigned)(tb + i) << 14) | ((unsigned)bal & 0x3FFFu);
            ++ecnt;                          // wave-uniform
        }
    }
    SR r; r.u = u; r.e = ecnt; return r;
}

#define REP14(M) M(0) M(1) M(2) M(3) M(4) M(5) M(6) M(7) M(8) M(9) M(10) M(11) M(12) M(13)
#define DECLA(j) f32x2 A##j;
#define DECLB(j) f32x2 B##j;
#define LDA0(j)  A##j = *(const f32x2*)&xr[(j)*T + tpa];
#define LDB1(j)  B##j = *(const f32x2*)&xr[(j)*T + tpb];
#define ZEROA(j) A##j = zz;
#define AJ(j) A##j
#define BJ(j) B##j

#define GEMM_C(SJ, cc, DB) { \
  f32x2 a_ = {0.f, 0.f}; \
  a_ = fma2(SJ(0),  wp(W1g[(cc)*14+0]),  a_); \
  a_ = fma2(SJ(1),  wp(W1g[(cc)*14+1]),  a_); \
  a_ = fma2(SJ(2),  wp(W1g[(cc)*14+2]),  a_); \
  a_ = fma2(SJ(3),  wp(W1g[(cc)*14+3]),  a_); \
  a_ = fma2(SJ(4),  wp(W1g[(cc)*14+4]),  a_); \
  a_ = fma2(SJ(5),  wp(W1g[(cc)*14+5]),  a_); \
  a_ = fma2(SJ(6),  wp(W1g[(cc)*14+6]),  a_); \
  a_ = fma2(SJ(7),  wp(W1g[(cc)*14+7]),  a_); \
  a_ = fma2(SJ(8),  wp(W1g[(cc)*14+8]),  a_); \
  a_ = fma2(SJ(9),  wp(W1g[(cc)*14+9]),  a_); \
  a_ = fma2(SJ(10), wp(W1g[(cc)*14+10]), a_); \
  a_ = fma2(SJ(11), wp(W1g[(cc)*14+11]), a_); \
  a_ = fma2(SJ(12), wp(W1g[(cc)*14+12]), a_); \
  a_ = fma2(SJ(13), wp(W1g[(cc)*14+13]), a_); \
  *(f32x2*)&(DB)[(cc)*DSTR + 2*lane] = a_; }

// one 16-step chain batch: prefetch NP, run spec chain on c0..c3, roll regs
#define CHB(TB, NP) { \
  const float* np_ = (NP); \
  const float4 n0_ = *(const float4*)&np_[0]; \
  const float4 n1_ = *(const float4*)&np_[4]; \
  const float4 n2_ = *(const float4*)&np_[8]; \
  const float4 n3_ = *(const float4*)&np_[12]; \
  float vv = u, m0, m1, m2, m3; \
  vv = fmaf(vv, 0.5f, c0.x); m0 = vv; \
  vv = fmaf(vv, 0.5f, c0.y); m1 = vv; \
  vv = fmaf(vv, 0.5f, c0.z); m2 = vv; \
  vv = fmaf(vv, 0.5f, c0.w); m3 = vv; \
  vv = fmaf(vv, 0.5f, c1.x); m0 = fmaxf(m0, vv); \
  vv = fmaf(vv, 0.5f, c1.y); m1 = fmaxf(m1, vv); \
  vv = fmaf(vv, 0.5f, c1.z); m2 = fmaxf(m2, vv); \
  vv = fmaf(vv, 0.5f, c1.w); m3 = fmaxf(m3, vv); \
  vv = fmaf(vv, 0.5f, c2.x); m0 = fmaxf(m0, vv); \
  vv = fmaf(vv, 0.5f, c2.y); m1 = fmaxf(m1, vv); \
  vv = fmaf(vv, 0.5f, c2.z); m2 = fmaxf(m2, vv); \
  vv = fmaf(vv, 0.5f, c2.w); m3 = fmaxf(m3, vv); \
  vv = fmaf(vv, 0.5f, c3.x); m0 = fmaxf(m0, vv); \
  vv = fmaf(vv, 0.5f, c3.y); m1 = fmaxf(m1, vv); \
  vv = fmaf(vv, 0.5f, c3.z); m2 = fmaxf(m2, vv); \
  vv = fmaf(vv, 0.5f, c3.w); m3 = fmaxf(m3, vv); \
  const float mx_ = fmaxf(fmaxf(m0, m1), fmaxf(m2, m3)); \
  if (__builtin_expect(__ballot(mx_ >= 14.0f) != 0ull, 0)) { \
    const SR r_ = slow_replay(u, c0, c1, c2, c3, (TB), lane, ecnt, (unsigned*)evs); \
    u = r_.u; ecnt = r_.e; \
  } else { u = vv; } \
  c0 = n0_; c1 = n1_; c2 = n2_; c3 = n3_; }

// first half of a window-pair: chain(2i) on db0 || GEMM(2i+1): B->db1 || loads->A
#define FH_BATCH(b, j0, j1) \
  CHB(tA + 16*(b), dp0 + 16*((b)+1)); \
  A##j0 = *(const f32x2*)&xr[(j0)*T + tn1]; \
  A##j1 = *(const f32x2*)&xr[(j1)*T + tn1]; \
  GEMM_C(BJ, j0, db1); \
  GEMM_C(BJ, j1, db1);

// second half: chain(2i+1) on db1 || GEMM(2i+2): A->db0 || loads->B (i==0 only)
#define SH_BATCH(b, j0, j1) \
  CHB(tB + 16*(b), dp1 + 16*((b)+1)); \
  if (i == 0) { \
    B##j0 = *(const f32x2*)&xr[(j0)*T + tn2]; \
    B##j1 = *(const f32x2*)&xr[(j1)*T + tn2]; \
  } \
  GEMM_C(AJ, j0, db0); \
  GEMM_C(AJ, j1, db0);

__global__ __launch_bounds__(64)
void snn_v11(const float* __restrict__ x, const float* __restrict__ W1g,
             const float* __restrict__ W2, float* __restrict__ out) {
    __shared__ float    db0[C * DSTR];
    __shared__ float    db1[C * DSTR];
    __shared__ unsigned evs[CAP];

    const int  lane = threadIdx.x;
    const long row  = blockIdx.x;
    const float* xr = &x[row * (long)(C * T)];
    const int  ce   = (lane < C) ? lane : (C - 1);

    REP14(DECLA)
    REP14(DECLB)

    // ---- prologue: window 0 -> A; GEMM(0) -> db0; window 1 -> B ----
    { const int tpa = 2 * lane; REP14(LDA0) }
    GEMM_C(AJ, 0, db0)  GEMM_C(AJ, 1, db0)  GEMM_C(AJ, 2, db0)
    GEMM_C(AJ, 3, db0)  GEMM_C(AJ, 4, db0)  GEMM_C(AJ, 5, db0)
    GEMM_C(AJ, 6, db0)  GEMM_C(AJ, 7, db0)  GEMM_C(AJ, 8, db0)
    GEMM_C(AJ, 9, db0)  GEMM_C(AJ, 10, db0) GEMM_C(AJ, 11, db0)
    GEMM_C(AJ, 12, db0) GEMM_C(AJ, 13, db0)
    { const int tpb = W + 2 * lane; REP14(LDB1) }

    float u = 0.f;                       // u = 2*v1 (exact pow2 scaling)
    int   ecnt = 0;
    const float* dp0 = &db0[ce * DSTR];
    const float* dp1 = &db1[ce * DSTR];
    float4 c0 = *(const float4*)&dp0[0];
    float4 c1 = *(const float4*)&dp0[4];
    float4 c2 = *(const float4*)&dp0[8];
    float4 c3 = *(const float4*)&dp0[12];

    for (int i = 0; i < 2; ++i) {
        const int tA = (2 * i) * W;
        const int tB = (2 * i + 1) * W;
        int tn1 = (2 * i + 2) * W + 2 * lane;        // loads -> A (win 2i+2)
        if (tn1 > T - 2) tn1 = T - 2;                // clamp (win4 tail; masked later)
        const int tn2 = 3 * W + 2 * lane;            // loads -> B (win 3, i==0)

        // ----- first half -----
        FH_BATCH(0, 0, 1)   FH_BATCH(1, 2, 3)   FH_BATCH(2, 4, 5)
        FH_BATCH(3, 6, 7)   FH_BATCH(4, 8, 9)   FH_BATCH(5, 10, 11)
        FH_BATCH(6, 12, 13)
        CHB(tA + 112, dp1)                           // batch 7 + prime next window

        // ----- second half -----
        if (i == 1 && lane >= (T - 4 * W) / 2) {     // zero win-4 tail steps (t>=600)
            const f32x2 zz = {0.f, 0.f};
            REP14(ZEROA)
        }
        SH_BATCH(0, 0, 1)   SH_BATCH(1, 2, 3)   SH_BATCH(2, 4, 5)
        SH_BATCH(3, 6, 7)   SH_BATCH(4, 8, 9)   SH_BATCH(5, 10, 11)
        SH_BATCH(6, 12, 13)
        CHB(tB + 112, dp0)                           // batch 7 + prime next window
    }

    // ----- epilogue: chain window 4 on db0 (88 steps + 8 exact-zero pads) -----
    CHB(512 + 0,  dp0 + 16)
    CHB(512 + 16, dp0 + 32)
    CHB(512 + 32, dp0 + 48)
    CHB(512 + 48, dp0 + 64)
    CHB(512 + 64, dp0 + 80)
    CHB(512 + 80, dp0)                               // last batch (dummy prefetch)

    // ===== event-driven LIF-2 + exp: 64 lanes x 8 outputs =====
    const int n = (ecnt < CAP) ? ecnt : CAP;
    float v2[8];
    #pragma unroll
    for (int k = 0; k < 8; ++k) v2[k] = 0.f;
    int tprev = -1;

    for (int e = 0; e < n; ++e) {
        const unsigned ev = evs[e];
        const int t = (int)(ev >> 14);
        unsigned mm = ev & 0x3FFFu;
        float i2[8];
        #pragma unroll
        for (int k = 0; k < 8; ++k) i2[k] = 0.f;
        while (mm) {                         // ascending channels = ref dot order
            const int c = (int)__builtin_ctz(mm);
            mm &= mm - 1;
            #pragma unroll
            for (int k = 0; k < 8; ++k) {
                const int o = lane + (k << 6);
                if (o < NOUT) i2[k] += W2[o * C + c];
            }
        }
        const int gap = t - tprev - 1;
        if (gap > 0) {                       // exact pure-decay run
            #pragma unroll
            for (int k = 0; k < 8; ++k) v2[k] = ldexpf(v2[k], -gap);
        }
        #pragma unroll
        for (int k = 0; k < 8; ++k) {
            const float v = v2[k] + (i2[k] - v2[k]) * 0.5f;   // ref-order charge
            v2[k] = (v >= 7.0f) ? 0.f : v;                    // hard reset
        }
        tprev = t;
    }
    {
        const int gap = (T - 1) - tprev;
        if (gap > 0) {
            #pragma unroll
            for (int k = 0; k < 8; ++k) v2[k] = ldexpf(v2[k], -gap);
        }
    }
    #pragma unroll
    for (int k = 0; k < 8; ++k) {
        const int o = lane + (k << 6);
        if (o < NOUT) out[row * NOUT + o] = expf(v2[k]);
    }
}

extern "C" void kernel_launch(void* const* d_in, const int* in_sizes, int n_in,
                              void* d_out, int out_size, void* d_ws, size_t ws_size,
                              hipStream_t stream) {
    const float* x  = (const float*)d_in[0];
    const float* W1 = (const float*)d_in[1];
    const float* W2 = (const float*)d_in[2];
    float* o = (float*)d_out;
    const int B = in_sizes[0] / (C * T);     // 4096
    snn_v11<<<B, 64, 0, stream>>>(x, W1, W2, o);
}